// Round 18
// baseline (79.213 us; speedup 1.0000x reference)
//
#include <hip/hip_runtime.h>
#include <hip/hip_bf16.h>

#define NA 3
#define NT 32
#define NC 4
#define NR 8
#define NK 1024
#define NPIX 4096            // 64*64
#define NOUT (NT * NC * NK)  // 131072 complex outputs
#define NRK (NR * NK)        // 8192 (r,k) pairs

typedef __attribute__((ext_vector_type(8))) short bf16x8;
typedef __attribute__((ext_vector_type(4))) float f32x4;

static __device__ __forceinline__ short f2bf(float f) {
    union { __hip_bfloat16 h; short s; } u;
    u.h = __float2bfloat16(f);
    return u.s;
}

// ---------------------------------------------------------------------------
// prep_pack: 24 blocks. Per-block detect scan of candA (|v|>pi => candA is
// mps; proven r7-r16), block 0 publishes flag; then 6144 pack jobs:
// sp[ch][n] = bf16(x[a,n]*mps[c,n]).   [byte-identical to r15/r16]
// ---------------------------------------------------------------------------
__global__ __launch_bounds__(256) void prep_pack(
    const float* __restrict__ x,
    const float* __restrict__ candA,
    const float* __restrict__ candB,
    int* __restrict__ flag,
    short* __restrict__ sp)
{
    __shared__ int sfl;
    if (threadIdx.x == 0) sfl = 0;
    __syncthreads();
    {
        const float4* A4 = (const float4*)candA;
        int loc = 0;
        for (int i = threadIdx.x; i < 4096; i += 256) {
            const float4 v = A4[i];
            if (fabsf(v.x) > 3.1416f || fabsf(v.y) > 3.1416f ||
                fabsf(v.z) > 3.1416f || fabsf(v.w) > 3.1416f) loc = 1;
        }
        if (loc) atomicOr(&sfl, 1);
    }
    __syncthreads();
    const int fl = sfl;
    if (blockIdx.x == 0 && threadIdx.x == 0) flag[0] = fl;
    const float* __restrict__ mps = fl ? candA : candB;

    const int job = blockIdx.x * 256 + threadIdx.x;   // 0..6143
    const int ch = job >> 9, p8 = (job & 511) * 8;
    const int a = ch >> 2, c = ch & 3;
    const float4 xv0 = *(const float4*)&x[a * NPIX + p8];
    const float4 xv1 = *(const float4*)&x[a * NPIX + p8 + 4];
    const float4 mv0 = *(const float4*)&mps[c * NPIX + p8];
    const float4 mv1 = *(const float4*)&mps[c * NPIX + p8 + 4];
    union { bf16x8 v; short s[8]; } pk;
    pk.s[0] = f2bf(xv0.x * mv0.x); pk.s[1] = f2bf(xv0.y * mv0.y);
    pk.s[2] = f2bf(xv0.z * mv0.z); pk.s[3] = f2bf(xv0.w * mv0.w);
    pk.s[4] = f2bf(xv1.x * mv1.x); pk.s[5] = f2bf(xv1.y * mv1.y);
    pk.s[6] = f2bf(xv1.z * mv1.z); pk.s[7] = f2bf(xv1.w * mv1.w);
    *(bf16x8*)(sp + ch * NPIX + p8) = pk.v;
}

// ---------------------------------------------------------------------------
// nudft_all8: r16's kernel with the VGPR cap REMOVED (no min-waves bound).
// Block = 16 rk, 512 thr = 8 waves; wave w -> (chgrp = w&3 -> 3 channels,
// ihalf = w>>2 -> 2 i-slices of 16).  In-register Ex/Ey phasors (r12-proven),
// A-fragments from global sp, 2 MFMAs (K=64) per (ch, slice), f32 Ey-fold.
// Partial y per ihalf -> ylds[2][12][16]; fused combine epilogue sums halves
// (planar f32 out, proven r7-r16).  Lane rule: A/B j-slots = g*8+e+32h
// (HW-perm invariant, r11-proven); C row = g*4+reg (m89-verified).
// ---------------------------------------------------------------------------
__global__ __launch_bounds__(512) void nudft_all8(
    const short* __restrict__ sp,
    const float* __restrict__ candA,
    const float* __restrict__ candB,
    const int*  __restrict__ flag,
    const float* __restrict__ phi,
    const float* __restrict__ dcf,
    const int*  __restrict__ sidx,
    float* __restrict__ out)
{
    __shared__ float2 ylds[2][12][16];

    const float* __restrict__ trj = flag[0] ? candB : candA;

    const int tid = threadIdx.x;
    const int w = tid >> 6, l = tid & 63, col = l & 15, g = l >> 4;
    const int chgrp = w & 3, ihalf = w >> 2;
    const int rk0 = blockIdx.x * 16;
    const int r = rk0 >> 10, k0 = rk0 & (NK - 1);
    const int k = k0 + col;

    const float t0 = trj[(r * 2 + 0) * NK + k];
    const float t1 = trj[(r * 2 + 1) * NK + k];

    // ---- Ex fragments in-register (r12-r16-proven) ----
    bf16x8 breh[2], bimh[2];
    {
        float pr[8], pi[8];
        float sr, cr; __sincosf(t1, &sr, &cr);
        float s0, c0; __sincosf(t1 * (float)(g * 8 - 32), &s0, &c0);
        pr[0] = c0; pi[0] = -s0;
#pragma unroll
        for (int e = 1; e < 8; ++e) {
            const float nr = pr[e-1] * cr + pi[e-1] * sr;
            const float ni = pi[e-1] * cr - pr[e-1] * sr;
            pr[e] = nr; pi[e] = ni;
        }
        union { bf16x8 v; short s[8]; } u0, u1;
#pragma unroll
        for (int e = 0; e < 8; ++e) { u0.s[e] = f2bf(pr[e]); u1.s[e] = f2bf(pi[e]); }
        breh[0] = u0.v; bimh[0] = u1.v;
        float s32, c32; __sincosf(32.f * t1, &s32, &c32);
#pragma unroll
        for (int e = 0; e < 8; ++e) {
            const float nr = pr[e] * c32 + pi[e] * s32;
            const float ni = pi[e] * c32 - pr[e] * s32;
            u0.s[e] = f2bf(nr); u1.s[e] = f2bf(ni);
        }
        breh[1] = u0.v; bimh[1] = u1.v;
    }

    // ---- Ey step rotation hoisted ----
    float syr, cyr; __sincosf(t0, &syr, &cyr);

    float yre[3] = {0.f, 0.f, 0.f}, yim[3] = {0.f, 0.f, 0.f};
#pragma unroll
    for (int sl = 0; sl < 2; ++sl) {
        const int i0 = ihalf * 32 + sl * 16;
        // Ey phasors: i = i0 + g*4 + reg (r12-r16-proven)
        float eyR[4], eyI[4];
        {
            float sb, cb; __sincosf(t0 * (float)(i0 + g * 4 - 32), &sb, &cb);
            eyR[0] = cb; eyI[0] = -sb;
#pragma unroll
            for (int q = 1; q < 4; ++q) {
                const float nr = eyR[q-1] * cyr + eyI[q-1] * syr;
                const float ni = eyI[q-1] * cyr - eyR[q-1] * syr;
                eyR[q] = nr; eyI[q] = ni;
            }
        }
#pragma unroll
        for (int cc = 0; cc < 3; ++cc) {
            const int ch = chgrp * 3 + cc;
            const short* ap = sp + ch * NPIX + (i0 + col) * 64 + g * 8;
            const bf16x8 a0 = *(const bf16x8*)ap;
            const bf16x8 a1 = *(const bf16x8*)(ap + 32);
            f32x4 gre = {0.f, 0.f, 0.f, 0.f}, gim = {0.f, 0.f, 0.f, 0.f};
            gre = __builtin_amdgcn_mfma_f32_16x16x32_bf16(a0, breh[0], gre, 0, 0, 0);
            gre = __builtin_amdgcn_mfma_f32_16x16x32_bf16(a1, breh[1], gre, 0, 0, 0);
            gim = __builtin_amdgcn_mfma_f32_16x16x32_bf16(a0, bimh[0], gim, 0, 0, 0);
            gim = __builtin_amdgcn_mfma_f32_16x16x32_bf16(a1, bimh[1], gim, 0, 0, 0);
#pragma unroll
            for (int reg = 0; reg < 4; ++reg) {
                yre[cc] = fmaf(eyR[reg], gre[reg], fmaf(-eyI[reg], gim[reg], yre[cc]));
                yim[cc] = fmaf(eyR[reg], gim[reg], fmaf( eyI[reg], gre[reg], yim[cc]));
            }
        }
    }

    // ---- reduce over g (lane bits 4,5), park partials in LDS ----
#pragma unroll
    for (int cc = 0; cc < 3; ++cc) {
        float vr = yre[cc], vi = yim[cc];
        vr += __shfl_xor(vr, 16); vi += __shfl_xor(vi, 16);
        vr += __shfl_xor(vr, 32); vi += __shfl_xor(vi, 32);
        if (g == 0) ylds[ihalf][chgrp * 3 + cc][col] = make_float2(vr, vi);
    }
    __syncthreads();

    // ---- fused combine epilogue (r13-r16-proven; sums the 2 i-halves) ----
    bool is64 = true;
#pragma unroll
    for (int i = 1; i < 32; i += 2) is64 = is64 && (sidx[i] == 0);
#pragma unroll
    for (int q = 0; q < 4; ++q) {
        const int item = tid + q * 512;          // 32t x 4c x 16k = 2048
        const int kl = item & 15;
        const int c  = (item >> 4) & 3;
        const int t  = item >> 6;
        const int rt = is64 ? sidx[2 * t] : sidx[t];
        if (rt == r) {
            const float d = dcf[r * NK + k0 + kl];
            float ore = 0.f, oim = 0.f;
#pragma unroll
            for (int a = 0; a < NA; ++a) {
                const float p = phi[a * NT + t];
                const float2 v0 = ylds[0][a * 4 + c][kl];
                const float2 v1 = ylds[1][a * 4 + c][kl];
                ore = fmaf(p, v0.x + v1.x, ore);
                oim = fmaf(p, v0.y + v1.y, oim);
            }
            const int gid = t * 4096 + c * 1024 + k0 + kl;
            out[gid]        = ore * d;
            out[NOUT + gid] = oim * d;
        }
    }
}

// ---------------------------------------------------------------------------
extern "C" void kernel_launch(void* const* d_in, const int* in_sizes, int n_in,
                              void* d_out, int out_size, void* d_ws, size_t ws_size,
                              hipStream_t stream) {
    // size-signature input resolution (robust to permutation; doc order default)
    int ix = 0, i16a = 1, iphi = 2, i16b = 3, idcf = 4, isidx = 5;
    int f16[2]; int n16 = 0, fx = -1, fphi = -1, fdcf = -1, fsidx = -1;
    for (int i = 0; i < n_in; ++i) {
        const int s = in_sizes[i];
        if (s == 12288) fx = i;
        else if (s == 96) fphi = i;
        else if (s == 8192) fdcf = i;
        else if (s == 16384) { if (n16 < 2) f16[n16] = i; ++n16; }
        else if (s == 32 || s == 64) fsidx = i;
    }
    if (fx >= 0 && fphi >= 0 && fdcf >= 0 && fsidx >= 0 && n16 == 2) {
        ix = fx; iphi = fphi; idcf = fdcf; isidx = fsidx;
        i16a = f16[0]; i16b = f16[1];
    }

    const float* x    = (const float*)d_in[ix];
    const float* cA   = (const float*)d_in[i16a];
    const float* cB   = (const float*)d_in[i16b];
    const float* phi  = (const float*)d_in[iphi];
    const float* dcf  = (const float*)d_in[idcf];
    const int*   sidx = (const int*)d_in[isidx];

    int*   flag = (int*)d_ws;                     // 256-B slot
    short* sp   = (short*)((char*)d_ws + 256);    // [12][4096] bf16 = 98304 B

    prep_pack<<<24, 256, 0, stream>>>(x, cA, cB, flag, sp);
    // MEASUREMENT ROUND: launch the (idempotent, overwrite-only) main kernel
    // 8x so dur_us reveals its true per-dispatch cost:
    //   main ~= (dur_us - fixed(~2.7) - prep(~2)) / 8
    for (int rep = 0; rep < 8; ++rep) {
        nudft_all8<<<NRK / 16, 512, 0, stream>>>(sp, cA, cB, flag, phi, dcf,
                                                 sidx, (float*)d_out);
    }
}

// Round 19
// 18.692 us; speedup vs baseline: 4.2378x; 4.2378x over previous
//
#include <hip/hip_runtime.h>
#include <hip/hip_bf16.h>

#define NA 3
#define NT 32
#define NC 4
#define NR 8
#define NK 1024
#define NPIX 4096            // 64*64
#define NOUT (NT * NC * NK)  // 131072 complex outputs
#define NRK (NR * NK)        // 8192 (r,k) pairs

typedef __attribute__((ext_vector_type(8))) short bf16x8;
typedef __attribute__((ext_vector_type(4))) float f32x4;

static __device__ __forceinline__ short f2bf(float f) {
    union { __hip_bfloat16 h; short s; } u;
    u.h = __float2bfloat16(f);
    return u.s;
}

// ---------------------------------------------------------------------------
// prep_pack: 24 blocks. Per-block detect scan of candA (|v|>pi => candA is
// mps; proven r7-r18), block 0 publishes flag; then 6144 pack jobs:
// sp[ch][n] = bf16(x[a,n]*mps[c,n]).   [byte-identical to r15-r18]
// ---------------------------------------------------------------------------
__global__ __launch_bounds__(256) void prep_pack(
    const float* __restrict__ x,
    const float* __restrict__ candA,
    const float* __restrict__ candB,
    int* __restrict__ flag,
    short* __restrict__ sp)
{
    __shared__ int sfl;
    if (threadIdx.x == 0) sfl = 0;
    __syncthreads();
    {
        const float4* A4 = (const float4*)candA;
        int loc = 0;
        for (int i = threadIdx.x; i < 4096; i += 256) {
            const float4 v = A4[i];
            if (fabsf(v.x) > 3.1416f || fabsf(v.y) > 3.1416f ||
                fabsf(v.z) > 3.1416f || fabsf(v.w) > 3.1416f) loc = 1;
        }
        if (loc) atomicOr(&sfl, 1);
    }
    __syncthreads();
    const int fl = sfl;
    if (blockIdx.x == 0 && threadIdx.x == 0) flag[0] = fl;
    const float* __restrict__ mps = fl ? candA : candB;

    const int job = blockIdx.x * 256 + threadIdx.x;   // 0..6143
    const int ch = job >> 9, p8 = (job & 511) * 8;
    const int a = ch >> 2, c = ch & 3;
    const float4 xv0 = *(const float4*)&x[a * NPIX + p8];
    const float4 xv1 = *(const float4*)&x[a * NPIX + p8 + 4];
    const float4 mv0 = *(const float4*)&mps[c * NPIX + p8];
    const float4 mv1 = *(const float4*)&mps[c * NPIX + p8 + 4];
    union { bf16x8 v; short s[8]; } pk;
    pk.s[0] = f2bf(xv0.x * mv0.x); pk.s[1] = f2bf(xv0.y * mv0.y);
    pk.s[2] = f2bf(xv0.z * mv0.z); pk.s[3] = f2bf(xv0.w * mv0.w);
    pk.s[4] = f2bf(xv1.x * mv1.x); pk.s[5] = f2bf(xv1.y * mv1.y);
    pk.s[6] = f2bf(xv1.z * mv1.z); pk.s[7] = f2bf(xv1.w * mv1.w);
    *(bf16x8*)(sp + ch * NPIX + p8) = pk.v;
}

// ---------------------------------------------------------------------------
// nudft_shared: r18's main kernel + setup-wave specialization.
// Block = 16 rk, 512 thr = 8 waves; wave w -> (chgrp = w&3, ihalf = w>>2).
// SETUP (one barrier): wave 0 computes the Ex MFMA B-fragments -> exlds
// (identical for all waves; r12-proven chains); waves 1/2 compute Ey phasor
// sets for ihalf 0/1 -> eylds (identical for the 4 waves sharing an ihalf).
// Values are bitwise-identical to every wave computing its own (r18).
// MAIN: per (ch, slice): 2 sp b128 loads, 2+2 MFMAs (K=64), f32 Ey-fold.
// Lane rule: A/B j-slots = g*8+e+32h (HW-perm invariant, r11-proven);
// C row = g*4+reg (m89-verified).  Epilogue: fused combine, planar f32 out
// (r7-r18-proven).  No occupancy cap (r18: cap caused spills).
// ---------------------------------------------------------------------------
__global__ __launch_bounds__(512) void nudft_shared(
    const short* __restrict__ sp,
    const float* __restrict__ candA,
    const float* __restrict__ candB,
    const int*  __restrict__ flag,
    const float* __restrict__ phi,
    const float* __restrict__ dcf,
    const int*  __restrict__ sidx,
    float* __restrict__ out)
{
    __shared__ short exlds[4][64][8];        // breh0,breh1,bimh0,bimh1  (4 KB)
    __shared__ float eylds[2][2][64][8];     // [ihalf][sl][lane][q*2+{re,im}] 8 KB
    __shared__ float2 ylds[2][12][16];

    const int tid = threadIdx.x;
    const int w = tid >> 6, l = tid & 63, col = l & 15, g = l >> 4;
    const int chgrp = w & 3, ihalf = w >> 2;
    const int rk0 = blockIdx.x * 16;
    const int r = rk0 >> 10, k0 = rk0 & (NK - 1);
    const int k = k0 + col;

    // ---- setup waves ----
    if (w == 0) {
        // Ex fragments (r12-r18-proven chains), written for every lane
        const float* __restrict__ trj = flag[0] ? candB : candA;
        const float t1 = trj[(r * 2 + 1) * NK + k];
        float pr[8], pi[8];
        float sr, cr; __sincosf(t1, &sr, &cr);
        float s0, c0; __sincosf(t1 * (float)(g * 8 - 32), &s0, &c0);
        pr[0] = c0; pi[0] = -s0;
#pragma unroll
        for (int e = 1; e < 8; ++e) {
            const float nr = pr[e-1] * cr + pi[e-1] * sr;
            const float ni = pi[e-1] * cr - pr[e-1] * sr;
            pr[e] = nr; pi[e] = ni;
        }
        union { bf16x8 v; short s[8]; } u0, u1;
#pragma unroll
        for (int e = 0; e < 8; ++e) { u0.s[e] = f2bf(pr[e]); u1.s[e] = f2bf(pi[e]); }
        *(bf16x8*)exlds[0][l] = u0.v;
        *(bf16x8*)exlds[2][l] = u1.v;
        float s32, c32; __sincosf(32.f * t1, &s32, &c32);
#pragma unroll
        for (int e = 0; e < 8; ++e) {
            const float nr = pr[e] * c32 + pi[e] * s32;
            const float ni = pi[e] * c32 - pr[e] * s32;
            u0.s[e] = f2bf(nr); u1.s[e] = f2bf(ni);
        }
        *(bf16x8*)exlds[1][l] = u0.v;
        *(bf16x8*)exlds[3][l] = u1.v;
    } else if (w == 1 || w == 2) {
        // Ey phasors for ihalf = w-1 (r12-r18-proven chains)
        const float* __restrict__ trj = flag[0] ? candB : candA;
        const float t0 = trj[(r * 2 + 0) * NK + k];
        const int ih = w - 1;
        float syr, cyr; __sincosf(t0, &syr, &cyr);
#pragma unroll
        for (int sl = 0; sl < 2; ++sl) {
            const int i0 = ih * 32 + sl * 16;
            float eyR[4], eyI[4];
            float sb, cb; __sincosf(t0 * (float)(i0 + g * 4 - 32), &sb, &cb);
            eyR[0] = cb; eyI[0] = -sb;
#pragma unroll
            for (int q = 1; q < 4; ++q) {
                const float nr = eyR[q-1] * cyr + eyI[q-1] * syr;
                const float ni = eyI[q-1] * cyr - eyR[q-1] * syr;
                eyR[q] = nr; eyI[q] = ni;
            }
            float* d = eylds[ih][sl][l];
#pragma unroll
            for (int q = 0; q < 4; ++q) { d[q * 2] = eyR[q]; d[q * 2 + 1] = eyI[q]; }
        }
    }
    __syncthreads();

    // ---- all waves: fragments from LDS ----
    const bf16x8 breh0 = *(const bf16x8*)exlds[0][l];
    const bf16x8 breh1 = *(const bf16x8*)exlds[1][l];
    const bf16x8 bimh0 = *(const bf16x8*)exlds[2][l];
    const bf16x8 bimh1 = *(const bf16x8*)exlds[3][l];

    float yre[3] = {0.f, 0.f, 0.f}, yim[3] = {0.f, 0.f, 0.f};
#pragma unroll
    for (int sl = 0; sl < 2; ++sl) {
        const int i0 = ihalf * 32 + sl * 16;
        const float* ey = eylds[ihalf][sl][l];
        float eyR[4], eyI[4];
#pragma unroll
        for (int q = 0; q < 4; ++q) { eyR[q] = ey[q * 2]; eyI[q] = ey[q * 2 + 1]; }
#pragma unroll
        for (int cc = 0; cc < 3; ++cc) {
            const int ch = chgrp * 3 + cc;
            const short* ap = sp + ch * NPIX + (i0 + col) * 64 + g * 8;
            const bf16x8 a0 = *(const bf16x8*)ap;
            const bf16x8 a1 = *(const bf16x8*)(ap + 32);
            f32x4 gre = {0.f, 0.f, 0.f, 0.f}, gim = {0.f, 0.f, 0.f, 0.f};
            gre = __builtin_amdgcn_mfma_f32_16x16x32_bf16(a0, breh0, gre, 0, 0, 0);
            gre = __builtin_amdgcn_mfma_f32_16x16x32_bf16(a1, breh1, gre, 0, 0, 0);
            gim = __builtin_amdgcn_mfma_f32_16x16x32_bf16(a0, bimh0, gim, 0, 0, 0);
            gim = __builtin_amdgcn_mfma_f32_16x16x32_bf16(a1, bimh1, gim, 0, 0, 0);
#pragma unroll
            for (int reg = 0; reg < 4; ++reg) {
                yre[cc] = fmaf(eyR[reg], gre[reg], fmaf(-eyI[reg], gim[reg], yre[cc]));
                yim[cc] = fmaf(eyR[reg], gim[reg], fmaf( eyI[reg], gre[reg], yim[cc]));
            }
        }
    }

    // ---- reduce over g (lane bits 4,5), park partials in LDS ----
#pragma unroll
    for (int cc = 0; cc < 3; ++cc) {
        float vr = yre[cc], vi = yim[cc];
        vr += __shfl_xor(vr, 16); vi += __shfl_xor(vi, 16);
        vr += __shfl_xor(vr, 32); vi += __shfl_xor(vi, 32);
        if (g == 0) ylds[ihalf][chgrp * 3 + cc][col] = make_float2(vr, vi);
    }
    __syncthreads();

    // ---- fused combine epilogue (r13-r18-proven; sums the 2 i-halves) ----
    bool is64 = true;
#pragma unroll
    for (int i = 1; i < 32; i += 2) is64 = is64 && (sidx[i] == 0);
#pragma unroll
    for (int q = 0; q < 4; ++q) {
        const int item = tid + q * 512;          // 32t x 4c x 16k = 2048
        const int kl = item & 15;
        const int c  = (item >> 4) & 3;
        const int t  = item >> 6;
        const int rt = is64 ? sidx[2 * t] : sidx[t];
        if (rt == r) {
            const float d = dcf[r * NK + k0 + kl];
            float ore = 0.f, oim = 0.f;
#pragma unroll
            for (int a = 0; a < NA; ++a) {
                const float p = phi[a * NT + t];
                const float2 v0 = ylds[0][a * 4 + c][kl];
                const float2 v1 = ylds[1][a * 4 + c][kl];
                ore = fmaf(p, v0.x + v1.x, ore);
                oim = fmaf(p, v0.y + v1.y, oim);
            }
            const int gid = t * 4096 + c * 1024 + k0 + kl;
            out[gid]        = ore * d;
            out[NOUT + gid] = oim * d;
        }
    }
}

// ---------------------------------------------------------------------------
extern "C" void kernel_launch(void* const* d_in, const int* in_sizes, int n_in,
                              void* d_out, int out_size, void* d_ws, size_t ws_size,
                              hipStream_t stream) {
    // size-signature input resolution (robust to permutation; doc order default)
    int ix = 0, i16a = 1, iphi = 2, i16b = 3, idcf = 4, isidx = 5;
    int f16[2]; int n16 = 0, fx = -1, fphi = -1, fdcf = -1, fsidx = -1;
    for (int i = 0; i < n_in; ++i) {
        const int s = in_sizes[i];
        if (s == 12288) fx = i;
        else if (s == 96) fphi = i;
        else if (s == 8192) fdcf = i;
        else if (s == 16384) { if (n16 < 2) f16[n16] = i; ++n16; }
        else if (s == 32 || s == 64) fsidx = i;
    }
    if (fx >= 0 && fphi >= 0 && fdcf >= 0 && fsidx >= 0 && n16 == 2) {
        ix = fx; iphi = fphi; idcf = fdcf; isidx = fsidx;
        i16a = f16[0]; i16b = f16[1];
    }

    const float* x    = (const float*)d_in[ix];
    const float* cA   = (const float*)d_in[i16a];
    const float* cB   = (const float*)d_in[i16b];
    const float* phi  = (const float*)d_in[iphi];
    const float* dcf  = (const float*)d_in[idcf];
    const int*   sidx = (const int*)d_in[isidx];

    int*   flag = (int*)d_ws;                     // 256-B slot
    short* sp   = (short*)((char*)d_ws + 256);    // [12][4096] bf16 = 98304 B

    prep_pack<<<24, 256, 0, stream>>>(x, cA, cB, flag, sp);
    nudft_shared<<<NRK / 16, 512, 0, stream>>>(sp, cA, cB, flag, phi, dcf,
                                               sidx, (float*)d_out);
}

// Round 20
// 17.963 us; speedup vs baseline: 4.4099x; 1.0406x over previous
//
#include <hip/hip_runtime.h>
#include <hip/hip_bf16.h>

#define NA 3
#define NT 32
#define NC 4
#define NR 8
#define NK 1024
#define NPIX 4096            // 64*64
#define NOUT (NT * NC * NK)  // 131072 complex outputs
#define NRK (NR * NK)        // 8192 (r,k) pairs

typedef __attribute__((ext_vector_type(8))) short bf16x8;
typedef __attribute__((ext_vector_type(4))) float f32x4;

static __device__ __forceinline__ short f2bf(float f) {
    union { __hip_bfloat16 h; short s; } u;
    u.h = __float2bfloat16(f);
    return u.s;
}

// ---------------------------------------------------------------------------
// prep_pack: 24 blocks. Per-block detect scan of candA (|v|>pi => candA is
// mps; proven r7-r19), block 0 publishes flag; then 6144 pack jobs:
// sp[ch][n] = bf16(x[a,n]*mps[c,n]).   [byte-identical to r15-r19]
// ---------------------------------------------------------------------------
__global__ __launch_bounds__(256) void prep_pack(
    const float* __restrict__ x,
    const float* __restrict__ candA,
    const float* __restrict__ candB,
    int* __restrict__ flag,
    short* __restrict__ sp)
{
    __shared__ int sfl;
    if (threadIdx.x == 0) sfl = 0;
    __syncthreads();
    {
        const float4* A4 = (const float4*)candA;
        int loc = 0;
        for (int i = threadIdx.x; i < 4096; i += 256) {
            const float4 v = A4[i];
            if (fabsf(v.x) > 3.1416f || fabsf(v.y) > 3.1416f ||
                fabsf(v.z) > 3.1416f || fabsf(v.w) > 3.1416f) loc = 1;
        }
        if (loc) atomicOr(&sfl, 1);
    }
    __syncthreads();
    const int fl = sfl;
    if (blockIdx.x == 0 && threadIdx.x == 0) flag[0] = fl;
    const float* __restrict__ mps = fl ? candA : candB;

    const int job = blockIdx.x * 256 + threadIdx.x;   // 0..6143
    const int ch = job >> 9, p8 = (job & 511) * 8;
    const int a = ch >> 2, c = ch & 3;
    const float4 xv0 = *(const float4*)&x[a * NPIX + p8];
    const float4 xv1 = *(const float4*)&x[a * NPIX + p8 + 4];
    const float4 mv0 = *(const float4*)&mps[c * NPIX + p8];
    const float4 mv1 = *(const float4*)&mps[c * NPIX + p8 + 4];
    union { bf16x8 v; short s[8]; } pk;
    pk.s[0] = f2bf(xv0.x * mv0.x); pk.s[1] = f2bf(xv0.y * mv0.y);
    pk.s[2] = f2bf(xv0.z * mv0.z); pk.s[3] = f2bf(xv0.w * mv0.w);
    pk.s[4] = f2bf(xv1.x * mv1.x); pk.s[5] = f2bf(xv1.y * mv1.y);
    pk.s[6] = f2bf(xv1.z * mv1.z); pk.s[7] = f2bf(xv1.w * mv1.w);
    *(bf16x8*)(sp + ch * NPIX + p8) = pk.v;
}

// ---------------------------------------------------------------------------
// nudft32: r18's (measured-fastest) kernel with block = 32 rk.
// 256 blocks (1 per CU, single scheduling round), 512 thr = 8 waves;
// wave w -> (chgrp = w&3 -> 3 channels, ihalf = w>>2 -> 2 i-slices of 16).
// Each wave handles TWO rk-groups (rkg = 0,1): each A-fragment load now
// feeds 8 MFMAs (2x A-reuse; sp traffic 50 MB -> 25 MB).
// In-register Ex/Ey phasors (r12-r19-proven chains); 2 MFMAs (K=64) per
// (rkg, ch, slice); f32 Ey-fold.  Lane rule: A/B j-slots = g*8+e+32h
// (HW-perm invariant, r11-proven); C row = g*4+reg (m89-verified).
// Epilogue: fused combine over 32 k, planar f32 out (r7-r19-proven).
// All arrays statically indexed via fully-unrolled loops (rule #20).
// ---------------------------------------------------------------------------
__global__ __launch_bounds__(512) void nudft32(
    const short* __restrict__ sp,
    const float* __restrict__ candA,
    const float* __restrict__ candB,
    const int*  __restrict__ flag,
    const float* __restrict__ phi,
    const float* __restrict__ dcf,
    const int*  __restrict__ sidx,
    float* __restrict__ out)
{
    __shared__ float2 ylds[2][12][32];   // [ihalf][ch][k-local]  6 KB

    const float* __restrict__ trj = flag[0] ? candB : candA;

    const int tid = threadIdx.x;
    const int w = tid >> 6, l = tid & 63, col = l & 15, g = l >> 4;
    const int chgrp = w & 3, ihalf = w >> 2;
    const int rk0 = blockIdx.x * 32;
    const int r = rk0 >> 10, k0 = rk0 & (NK - 1);

    float t0a[2], t1a[2];
#pragma unroll
    for (int q = 0; q < 2; ++q) {
        const int k = k0 + q * 16 + col;
        t0a[q] = trj[(r * 2 + 0) * NK + k];
        t1a[q] = trj[(r * 2 + 1) * NK + k];
    }

    // ---- Ex fragments for both rk-groups (r12-r19-proven chains) ----
    bf16x8 bre[2][2], bim[2][2];
#pragma unroll
    for (int q = 0; q < 2; ++q) {
        float pr[8], pi[8];
        float sr, cr; __sincosf(t1a[q], &sr, &cr);
        float s0, c0; __sincosf(t1a[q] * (float)(g * 8 - 32), &s0, &c0);
        pr[0] = c0; pi[0] = -s0;
#pragma unroll
        for (int e = 1; e < 8; ++e) {
            const float nr = pr[e-1] * cr + pi[e-1] * sr;
            const float ni = pi[e-1] * cr - pr[e-1] * sr;
            pr[e] = nr; pi[e] = ni;
        }
        union { bf16x8 v; short s[8]; } u0, u1;
#pragma unroll
        for (int e = 0; e < 8; ++e) { u0.s[e] = f2bf(pr[e]); u1.s[e] = f2bf(pi[e]); }
        bre[q][0] = u0.v; bim[q][0] = u1.v;
        float s32, c32; __sincosf(32.f * t1a[q], &s32, &c32);
#pragma unroll
        for (int e = 0; e < 8; ++e) {
            const float nr = pr[e] * c32 + pi[e] * s32;
            const float ni = pi[e] * c32 - pr[e] * s32;
            u0.s[e] = f2bf(nr); u1.s[e] = f2bf(ni);
        }
        bre[q][1] = u0.v; bim[q][1] = u1.v;
    }

    // ---- Ey step rotations hoisted ----
    float syr[2], cyr[2];
#pragma unroll
    for (int q = 0; q < 2; ++q) __sincosf(t0a[q], &syr[q], &cyr[q]);

    float yre[2][3] = {{0.f,0.f,0.f},{0.f,0.f,0.f}};
    float yim[2][3] = {{0.f,0.f,0.f},{0.f,0.f,0.f}};

#pragma unroll
    for (int sl = 0; sl < 2; ++sl) {
        const int i0 = ihalf * 32 + sl * 16;
        // Ey phasors per rk-group: i = i0 + g*4 + reg (r12-r19-proven)
        float eyR[2][4], eyI[2][4];
#pragma unroll
        for (int q = 0; q < 2; ++q) {
            float sb, cb; __sincosf(t0a[q] * (float)(i0 + g * 4 - 32), &sb, &cb);
            eyR[q][0] = cb; eyI[q][0] = -sb;
#pragma unroll
            for (int j = 1; j < 4; ++j) {
                const float nr = eyR[q][j-1] * cyr[q] + eyI[q][j-1] * syr[q];
                const float ni = eyI[q][j-1] * cyr[q] - eyR[q][j-1] * syr[q];
                eyR[q][j] = nr; eyI[q][j] = ni;
            }
        }
#pragma unroll
        for (int cc = 0; cc < 3; ++cc) {
            const int ch = chgrp * 3 + cc;
            const short* ap = sp + ch * NPIX + (i0 + col) * 64 + g * 8;
            const bf16x8 a0 = *(const bf16x8*)ap;        // shared by both rkg
            const bf16x8 a1 = *(const bf16x8*)(ap + 32);
#pragma unroll
            for (int q = 0; q < 2; ++q) {
                f32x4 gre = {0.f, 0.f, 0.f, 0.f}, gim = {0.f, 0.f, 0.f, 0.f};
                gre = __builtin_amdgcn_mfma_f32_16x16x32_bf16(a0, bre[q][0], gre, 0, 0, 0);
                gre = __builtin_amdgcn_mfma_f32_16x16x32_bf16(a1, bre[q][1], gre, 0, 0, 0);
                gim = __builtin_amdgcn_mfma_f32_16x16x32_bf16(a0, bim[q][0], gim, 0, 0, 0);
                gim = __builtin_amdgcn_mfma_f32_16x16x32_bf16(a1, bim[q][1], gim, 0, 0, 0);
#pragma unroll
                for (int reg = 0; reg < 4; ++reg) {
                    yre[q][cc] = fmaf(eyR[q][reg], gre[reg],
                                  fmaf(-eyI[q][reg], gim[reg], yre[q][cc]));
                    yim[q][cc] = fmaf(eyR[q][reg], gim[reg],
                                  fmaf( eyI[q][reg], gre[reg], yim[q][cc]));
                }
            }
        }
    }

    // ---- reduce over g (lane bits 4,5), park partials in LDS ----
#pragma unroll
    for (int q = 0; q < 2; ++q) {
#pragma unroll
        for (int cc = 0; cc < 3; ++cc) {
            float vr = yre[q][cc], vi = yim[q][cc];
            vr += __shfl_xor(vr, 16); vi += __shfl_xor(vi, 16);
            vr += __shfl_xor(vr, 32); vi += __shfl_xor(vi, 32);
            if (g == 0)
                ylds[ihalf][chgrp * 3 + cc][q * 16 + col] = make_float2(vr, vi);
        }
    }
    __syncthreads();

    // ---- fused combine epilogue over 32 k (r13-r19-proven; planar f32) ----
    bool is64 = true;
#pragma unroll
    for (int i = 1; i < 32; i += 2) is64 = is64 && (sidx[i] == 0);
#pragma unroll
    for (int q = 0; q < 8; ++q) {
        const int item = tid + q * 512;          // 32t x 4c x 32k = 4096
        const int kl = item & 31;
        const int c  = (item >> 5) & 3;
        const int t  = item >> 7;
        const int rt = is64 ? sidx[2 * t] : sidx[t];
        if (rt == r) {
            const float d = dcf[r * NK + k0 + kl];
            float ore = 0.f, oim = 0.f;
#pragma unroll
            for (int a = 0; a < NA; ++a) {
                const float p = phi[a * NT + t];
                const float2 v0 = ylds[0][a * 4 + c][kl];
                const float2 v1 = ylds[1][a * 4 + c][kl];
                ore = fmaf(p, v0.x + v1.x, ore);
                oim = fmaf(p, v0.y + v1.y, oim);
            }
            const int gid = t * 4096 + c * 1024 + k0 + kl;
            out[gid]        = ore * d;
            out[NOUT + gid] = oim * d;
        }
    }
}

// ---------------------------------------------------------------------------
extern "C" void kernel_launch(void* const* d_in, const int* in_sizes, int n_in,
                              void* d_out, int out_size, void* d_ws, size_t ws_size,
                              hipStream_t stream) {
    // size-signature input resolution (robust to permutation; doc order default)
    int ix = 0, i16a = 1, iphi = 2, i16b = 3, idcf = 4, isidx = 5;
    int f16[2]; int n16 = 0, fx = -1, fphi = -1, fdcf = -1, fsidx = -1;
    for (int i = 0; i < n_in; ++i) {
        const int s = in_sizes[i];
        if (s == 12288) fx = i;
        else if (s == 96) fphi = i;
        else if (s == 8192) fdcf = i;
        else if (s == 16384) { if (n16 < 2) f16[n16] = i; ++n16; }
        else if (s == 32 || s == 64) fsidx = i;
    }
    if (fx >= 0 && fphi >= 0 && fdcf >= 0 && fsidx >= 0 && n16 == 2) {
        ix = fx; iphi = fphi; idcf = fdcf; isidx = fsidx;
        i16a = f16[0]; i16b = f16[1];
    }

    const float* x    = (const float*)d_in[ix];
    const float* cA   = (const float*)d_in[i16a];
    const float* cB   = (const float*)d_in[i16b];
    const float* phi  = (const float*)d_in[iphi];
    const float* dcf  = (const float*)d_in[idcf];
    const int*   sidx = (const int*)d_in[isidx];

    int*   flag = (int*)d_ws;                     // 256-B slot
    short* sp   = (short*)((char*)d_ws + 256);    // [12][4096] bf16 = 98304 B

    prep_pack<<<24, 256, 0, stream>>>(x, cA, cB, flag, sp);
    nudft32<<<NRK / 32, 512, 0, stream>>>(sp, cA, cB, flag, phi, dcf, sidx,
                                          (float*)d_out);
}

// Round 21
// 16.484 us; speedup vs baseline: 4.8053x; 1.0897x over previous
//
#include <hip/hip_runtime.h>
#include <hip/hip_bf16.h>

#define NA 3
#define NT 32
#define NC 4
#define NR 8
#define NK 1024
#define NPIX 4096            // 64*64
#define NOUT (NT * NC * NK)  // 131072 complex outputs
#define NRK (NR * NK)        // 8192 (r,k) pairs
#define SP_LDS_BYTES 98304   // [12][4096] bf16, XOR-swizzled rows

typedef __attribute__((ext_vector_type(8))) short bf16x8;
typedef __attribute__((ext_vector_type(4))) float f32x4;

static __device__ __forceinline__ short f2bf(float f) {
    union { __hip_bfloat16 h; short s; } u;
    u.h = __float2bfloat16(f);
    return u.s;
}

// ---------------------------------------------------------------------------
// nudft_mono2: ONE dispatch for the whole pipeline.
//  phase 0: inline detect (r13/r17-proven semantics): 512 thr scan all of
//           candA; any |v| > pi => candA is mps (P(false-neg) ~ 2e-12).
//  phase 1: block packs the FULL s' image into dynamic LDS once:
//           lds[ch][n] = bf16(x[a,n]*mps[c,n])  (bitwise = r15-r20's sp),
//           byte addresses XOR-swizzled with ((row&7)<<4) so the main
//           phase's 128-B-stride b128 reads are bank-conflict-free (G4;
//           both store & load swizzled with the same involution, G21).
//  phase 2: r20's main loop (block = 32 rk, 8 waves, chgrp/ihalf split,
//           2 rk-groups per A-load): in-register Ex/Ey phasors (r12-r19-
//           proven chains), 2 MFMAs (K=64) per (rkg,ch,slice), f32 Ey-fold.
//           Lane rule: A/B j-slots = g*8+e+32h (HW-perm invariant, r11);
//           C row = g*4+reg (m89-verified).
//  phase 3: fused combine epilogue, planar f32 out (r7-r20-proven).
// ---------------------------------------------------------------------------
__global__ __launch_bounds__(512) void nudft_mono2(
    const float* __restrict__ x,
    const float* __restrict__ candA,
    const float* __restrict__ candB,
    const float* __restrict__ phi,
    const float* __restrict__ dcf,
    const int*  __restrict__ sidx,
    float* __restrict__ out)
{
    extern __shared__ char lds[];            // SP_LDS_BYTES swizzled s'
    __shared__ int sfl;
    __shared__ float2 ylds[2][12][32];       // [ihalf][ch][k-local]

    const int tid = threadIdx.x;

    // ---- phase 0: detect ----
    if (tid == 0) sfl = 0;
    __syncthreads();
    {
        const float4* A4 = (const float4*)candA;
        int loc = 0;
#pragma unroll
        for (int q = 0; q < 8; ++q) {
            const float4 v = A4[tid + q * 512];
            if (fabsf(v.x) > 3.1416f || fabsf(v.y) > 3.1416f ||
                fabsf(v.z) > 3.1416f || fabsf(v.w) > 3.1416f) loc = 1;
        }
        if (loc) atomicOr(&sfl, 1);
    }
    __syncthreads();
    const int fl = sfl;
    const float* __restrict__ trj = fl ? candB : candA;
    const float* __restrict__ mps = fl ? candA : candB;

    // ---- phase 1: cooperative pack into swizzled LDS ----
#pragma unroll
    for (int jj = 0; jj < 12; ++jj) {
        const int job = tid + jj * 512;              // 0..6143
        const int ch = job >> 9, p8 = (job & 511) * 8;
        const int a = ch >> 2, c = ch & 3;
        const float4 xv0 = *(const float4*)&x[a * NPIX + p8];
        const float4 xv1 = *(const float4*)&x[a * NPIX + p8 + 4];
        const float4 mv0 = *(const float4*)&mps[c * NPIX + p8];
        const float4 mv1 = *(const float4*)&mps[c * NPIX + p8 + 4];
        union { bf16x8 v; short s[8]; } pk;
        pk.s[0] = f2bf(xv0.x * mv0.x); pk.s[1] = f2bf(xv0.y * mv0.y);
        pk.s[2] = f2bf(xv0.z * mv0.z); pk.s[3] = f2bf(xv0.w * mv0.w);
        pk.s[4] = f2bf(xv1.x * mv1.x); pk.s[5] = f2bf(xv1.y * mv1.y);
        pk.s[6] = f2bf(xv1.z * mv1.z); pk.s[7] = f2bf(xv1.w * mv1.w);
        const int row = p8 >> 6;                     // image row (j-run)
        const int byteoff = (ch * 8192 + p8 * 2) ^ ((row & 7) << 4);
        *(bf16x8*)(lds + byteoff) = pk.v;
    }
    __syncthreads();

    // ---- phase 2: main (r20 structure, A-fragments from LDS) ----
    const int w = tid >> 6, l = tid & 63, col = l & 15, g = l >> 4;
    const int chgrp = w & 3, ihalf = w >> 2;
    const int rk0 = blockIdx.x * 32;
    const int r = rk0 >> 10, k0 = rk0 & (NK - 1);

    float t0a[2], t1a[2];
#pragma unroll
    for (int q = 0; q < 2; ++q) {
        const int k = k0 + q * 16 + col;
        t0a[q] = trj[(r * 2 + 0) * NK + k];
        t1a[q] = trj[(r * 2 + 1) * NK + k];
    }

    // Ex fragments for both rk-groups (r12-r20-proven chains)
    bf16x8 bre[2][2], bim[2][2];
#pragma unroll
    for (int q = 0; q < 2; ++q) {
        float pr[8], pi[8];
        float sr, cr; __sincosf(t1a[q], &sr, &cr);
        float s0, c0; __sincosf(t1a[q] * (float)(g * 8 - 32), &s0, &c0);
        pr[0] = c0; pi[0] = -s0;
#pragma unroll
        for (int e = 1; e < 8; ++e) {
            const float nr = pr[e-1] * cr + pi[e-1] * sr;
            const float ni = pi[e-1] * cr - pr[e-1] * sr;
            pr[e] = nr; pi[e] = ni;
        }
        union { bf16x8 v; short s[8]; } u0, u1;
#pragma unroll
        for (int e = 0; e < 8; ++e) { u0.s[e] = f2bf(pr[e]); u1.s[e] = f2bf(pi[e]); }
        bre[q][0] = u0.v; bim[q][0] = u1.v;
        float s32, c32; __sincosf(32.f * t1a[q], &s32, &c32);
#pragma unroll
        for (int e = 0; e < 8; ++e) {
            const float nr = pr[e] * c32 + pi[e] * s32;
            const float ni = pi[e] * c32 - pr[e] * s32;
            u0.s[e] = f2bf(nr); u1.s[e] = f2bf(ni);
        }
        bre[q][1] = u0.v; bim[q][1] = u1.v;
    }

    float syr[2], cyr[2];
#pragma unroll
    for (int q = 0; q < 2; ++q) __sincosf(t0a[q], &syr[q], &cyr[q]);

    float yre[2][3] = {{0.f,0.f,0.f},{0.f,0.f,0.f}};
    float yim[2][3] = {{0.f,0.f,0.f},{0.f,0.f,0.f}};

#pragma unroll
    for (int sl = 0; sl < 2; ++sl) {
        const int i0 = ihalf * 32 + sl * 16;
        float eyR[2][4], eyI[2][4];
#pragma unroll
        for (int q = 0; q < 2; ++q) {
            float sb, cb; __sincosf(t0a[q] * (float)(i0 + g * 4 - 32), &sb, &cb);
            eyR[q][0] = cb; eyI[q][0] = -sb;
#pragma unroll
            for (int j = 1; j < 4; ++j) {
                const float nr = eyR[q][j-1] * cyr[q] + eyI[q][j-1] * syr[q];
                const float ni = eyI[q][j-1] * cyr[q] - eyR[q][j-1] * syr[q];
                eyR[q][j] = nr; eyI[q][j] = ni;
            }
        }
#pragma unroll
        for (int cc = 0; cc < 3; ++cc) {
            const int ch = chgrp * 3 + cc;
            // swizzled LDS read: linear byte = ch*8192 + (i0+col)*128 + g*16
            const int lin = ch * 8192 + (i0 + col) * 128 + g * 16;
            const int sw  = (col & 7) << 4;          // ((i0+col)&7)<<4, i0%16==0
            const bf16x8 a0 = *(const bf16x8*)(lds + (lin ^ sw));
            const bf16x8 a1 = *(const bf16x8*)(lds + ((lin + 64) ^ sw));
#pragma unroll
            for (int q = 0; q < 2; ++q) {
                f32x4 gre = {0.f, 0.f, 0.f, 0.f}, gim = {0.f, 0.f, 0.f, 0.f};
                gre = __builtin_amdgcn_mfma_f32_16x16x32_bf16(a0, bre[q][0], gre, 0, 0, 0);
                gre = __builtin_amdgcn_mfma_f32_16x16x32_bf16(a1, bre[q][1], gre, 0, 0, 0);
                gim = __builtin_amdgcn_mfma_f32_16x16x32_bf16(a0, bim[q][0], gim, 0, 0, 0);
                gim = __builtin_amdgcn_mfma_f32_16x16x32_bf16(a1, bim[q][1], gim, 0, 0, 0);
#pragma unroll
                for (int reg = 0; reg < 4; ++reg) {
                    yre[q][cc] = fmaf(eyR[q][reg], gre[reg],
                                  fmaf(-eyI[q][reg], gim[reg], yre[q][cc]));
                    yim[q][cc] = fmaf(eyR[q][reg], gim[reg],
                                  fmaf( eyI[q][reg], gre[reg], yim[q][cc]));
                }
            }
        }
    }

    // reduce over g (lane bits 4,5), park partials in LDS
#pragma unroll
    for (int q = 0; q < 2; ++q) {
#pragma unroll
        for (int cc = 0; cc < 3; ++cc) {
            float vr = yre[q][cc], vi = yim[q][cc];
            vr += __shfl_xor(vr, 16); vi += __shfl_xor(vi, 16);
            vr += __shfl_xor(vr, 32); vi += __shfl_xor(vi, 32);
            if (g == 0)
                ylds[ihalf][chgrp * 3 + cc][q * 16 + col] = make_float2(vr, vi);
        }
    }
    __syncthreads();

    // ---- phase 3: fused combine epilogue (planar f32 out, proven) ----
    bool is64 = true;
#pragma unroll
    for (int i = 1; i < 32; i += 2) is64 = is64 && (sidx[i] == 0);
#pragma unroll
    for (int q = 0; q < 8; ++q) {
        const int item = tid + q * 512;          // 32t x 4c x 32k = 4096
        const int kl = item & 31;
        const int c  = (item >> 5) & 3;
        const int t  = item >> 7;
        const int rt = is64 ? sidx[2 * t] : sidx[t];
        if (rt == r) {
            const float d = dcf[r * NK + k0 + kl];
            float ore = 0.f, oim = 0.f;
#pragma unroll
            for (int a = 0; a < NA; ++a) {
                const float p = phi[a * NT + t];
                const float2 v0 = ylds[0][a * 4 + c][kl];
                const float2 v1 = ylds[1][a * 4 + c][kl];
                ore = fmaf(p, v0.x + v1.x, ore);
                oim = fmaf(p, v0.y + v1.y, oim);
            }
            const int gid = t * 4096 + c * 1024 + k0 + kl;
            out[gid]        = ore * d;
            out[NOUT + gid] = oim * d;
        }
    }
}

// ---------------------------------------------------------------------------
extern "C" void kernel_launch(void* const* d_in, const int* in_sizes, int n_in,
                              void* d_out, int out_size, void* d_ws, size_t ws_size,
                              hipStream_t stream) {
    // size-signature input resolution (robust to permutation; doc order default)
    int ix = 0, i16a = 1, iphi = 2, i16b = 3, idcf = 4, isidx = 5;
    int f16[2]; int n16 = 0, fx = -1, fphi = -1, fdcf = -1, fsidx = -1;
    for (int i = 0; i < n_in; ++i) {
        const int s = in_sizes[i];
        if (s == 12288) fx = i;
        else if (s == 96) fphi = i;
        else if (s == 8192) fdcf = i;
        else if (s == 16384) { if (n16 < 2) f16[n16] = i; ++n16; }
        else if (s == 32 || s == 64) fsidx = i;
    }
    if (fx >= 0 && fphi >= 0 && fdcf >= 0 && fsidx >= 0 && n16 == 2) {
        ix = fx; iphi = fphi; idcf = fdcf; isidx = fsidx;
        i16a = f16[0]; i16b = f16[1];
    }

    // allow >64 KiB dynamic LDS (no-op if already permitted)
    static bool attr_set = false;
    if (!attr_set) {
        hipFuncSetAttribute((const void*)nudft_mono2,
                            hipFuncAttributeMaxDynamicSharedMemorySize,
                            SP_LDS_BYTES);
        attr_set = true;
    }

    nudft_mono2<<<NRK / 32, 512, SP_LDS_BYTES, stream>>>(
        (const float*)d_in[ix], (const float*)d_in[i16a], (const float*)d_in[i16b],
        (const float*)d_in[iphi], (const float*)d_in[idcf], (const int*)d_in[isidx],
        (float*)d_out);
}

// Round 22
// 16.150 us; speedup vs baseline: 4.9048x; 1.0207x over previous
//
#include <hip/hip_runtime.h>
#include <hip/hip_bf16.h>

#define NA 3
#define NT 32
#define NC 4
#define NR 8
#define NK 1024
#define NPIX 4096            // 64*64
#define NOUT (NT * NC * NK)  // 131072 complex outputs
#define NRK (NR * NK)        // 8192 (r,k) pairs
#define SP_LDS_BYTES 98304   // [12][4096] bf16, XOR-swizzled rows

typedef __attribute__((ext_vector_type(8))) short bf16x8;
typedef __attribute__((ext_vector_type(4))) float f32x4;

static __device__ __forceinline__ short f2bf(float f) {
    union { __hip_bfloat16 h; short s; } u;
    u.h = __float2bfloat16(f);
    return u.s;
}

// ---------------------------------------------------------------------------
// nudft_mono16: r21's single-dispatch pipeline, 16 waves/block (1024 thr).
//  phase 0: inline detect (proven r13-r21): any |candA| > pi => candA is mps.
//  phase 1: cooperative pack of full s' into swizzled dynamic LDS
//           (lds[ch][n] = bf16(x*mps), byte ^= ((row&7)<<4); bitwise = r21).
//  phase 2: wave w -> (chgrp = w&3 -> 3 channels, iq = w>>2 -> ONE 16-row
//           i-slice).  2 rk-groups per A-load (r20); in-register Ex/Ey
//           phasors (r12-r21-proven chains); 2 MFMAs (K=64) per (rkg,ch);
//           f32 Ey-fold.  Lane rule: A/B j-slots = g*8+e+32h (r11-proven);
//           C row = g*4+reg (m89).  Partials -> ylds[4][12][32].
//  phase 3: fused combine epilogue sums 4 partials; planar f32 out
//           (r7-r21-proven layout).
// ---------------------------------------------------------------------------
__global__ __launch_bounds__(1024) void nudft_mono16(
    const float* __restrict__ x,
    const float* __restrict__ candA,
    const float* __restrict__ candB,
    const float* __restrict__ phi,
    const float* __restrict__ dcf,
    const int*  __restrict__ sidx,
    float* __restrict__ out)
{
    extern __shared__ char lds[];            // SP_LDS_BYTES swizzled s'
    __shared__ int sfl;
    __shared__ float2 ylds[4][12][32];       // [iq][ch][k-local] 12 KB

    const int tid = threadIdx.x;

    // ---- phase 0: detect ----
    if (tid == 0) sfl = 0;
    __syncthreads();
    {
        const float4* A4 = (const float4*)candA;
        int loc = 0;
#pragma unroll
        for (int q = 0; q < 4; ++q) {
            const float4 v = A4[tid + q * 1024];
            if (fabsf(v.x) > 3.1416f || fabsf(v.y) > 3.1416f ||
                fabsf(v.z) > 3.1416f || fabsf(v.w) > 3.1416f) loc = 1;
        }
        if (loc) atomicOr(&sfl, 1);
    }
    __syncthreads();
    const int fl = sfl;
    const float* __restrict__ trj = fl ? candB : candA;
    const float* __restrict__ mps = fl ? candA : candB;

    // ---- phase 1: cooperative pack into swizzled LDS ----
#pragma unroll
    for (int jj = 0; jj < 6; ++jj) {
        const int job = tid + jj * 1024;             // 0..6143
        const int ch = job >> 9, p8 = (job & 511) * 8;
        const int a = ch >> 2, c = ch & 3;
        const float4 xv0 = *(const float4*)&x[a * NPIX + p8];
        const float4 xv1 = *(const float4*)&x[a * NPIX + p8 + 4];
        const float4 mv0 = *(const float4*)&mps[c * NPIX + p8];
        const float4 mv1 = *(const float4*)&mps[c * NPIX + p8 + 4];
        union { bf16x8 v; short s[8]; } pk;
        pk.s[0] = f2bf(xv0.x * mv0.x); pk.s[1] = f2bf(xv0.y * mv0.y);
        pk.s[2] = f2bf(xv0.z * mv0.z); pk.s[3] = f2bf(xv0.w * mv0.w);
        pk.s[4] = f2bf(xv1.x * mv1.x); pk.s[5] = f2bf(xv1.y * mv1.y);
        pk.s[6] = f2bf(xv1.z * mv1.z); pk.s[7] = f2bf(xv1.w * mv1.w);
        const int row = p8 >> 6;                     // image row (j-run)
        const int byteoff = (ch * 8192 + p8 * 2) ^ ((row & 7) << 4);
        *(bf16x8*)(lds + byteoff) = pk.v;
    }
    __syncthreads();

    // ---- phase 2: main ----
    const int w = tid >> 6, l = tid & 63, col = l & 15, g = l >> 4;
    const int chgrp = w & 3, iq = w >> 2;            // iq in 0..3
    const int rk0 = blockIdx.x * 32;
    const int r = rk0 >> 10, k0 = rk0 & (NK - 1);
    const int i0 = iq * 16;

    float t0a[2], t1a[2];
#pragma unroll
    for (int q = 0; q < 2; ++q) {
        const int k = k0 + q * 16 + col;
        t0a[q] = trj[(r * 2 + 0) * NK + k];
        t1a[q] = trj[(r * 2 + 1) * NK + k];
    }

    // Ex fragments for both rk-groups (r12-r21-proven chains)
    bf16x8 bre[2][2], bim[2][2];
#pragma unroll
    for (int q = 0; q < 2; ++q) {
        float pr[8], pi[8];
        float sr, cr; __sincosf(t1a[q], &sr, &cr);
        float s0, c0; __sincosf(t1a[q] * (float)(g * 8 - 32), &s0, &c0);
        pr[0] = c0; pi[0] = -s0;
#pragma unroll
        for (int e = 1; e < 8; ++e) {
            const float nr = pr[e-1] * cr + pi[e-1] * sr;
            const float ni = pi[e-1] * cr - pr[e-1] * sr;
            pr[e] = nr; pi[e] = ni;
        }
        union { bf16x8 v; short s[8]; } u0, u1;
#pragma unroll
        for (int e = 0; e < 8; ++e) { u0.s[e] = f2bf(pr[e]); u1.s[e] = f2bf(pi[e]); }
        bre[q][0] = u0.v; bim[q][0] = u1.v;
        float s32, c32; __sincosf(32.f * t1a[q], &s32, &c32);
#pragma unroll
        for (int e = 0; e < 8; ++e) {
            const float nr = pr[e] * c32 + pi[e] * s32;
            const float ni = pi[e] * c32 - pr[e] * s32;
            u0.s[e] = f2bf(nr); u1.s[e] = f2bf(ni);
        }
        bre[q][1] = u0.v; bim[q][1] = u1.v;
    }

    // Ey phasors: i = i0 + g*4 + reg (one slice per wave)
    float eyR[2][4], eyI[2][4];
#pragma unroll
    for (int q = 0; q < 2; ++q) {
        float syr, cyr; __sincosf(t0a[q], &syr, &cyr);
        float sb, cb; __sincosf(t0a[q] * (float)(i0 + g * 4 - 32), &sb, &cb);
        eyR[q][0] = cb; eyI[q][0] = -sb;
#pragma unroll
        for (int j = 1; j < 4; ++j) {
            const float nr = eyR[q][j-1] * cyr + eyI[q][j-1] * syr;
            const float ni = eyI[q][j-1] * cyr - eyR[q][j-1] * syr;
            eyR[q][j] = nr; eyI[q][j] = ni;
        }
    }

    float yre[2][3] = {{0.f,0.f,0.f},{0.f,0.f,0.f}};
    float yim[2][3] = {{0.f,0.f,0.f},{0.f,0.f,0.f}};

#pragma unroll
    for (int cc = 0; cc < 3; ++cc) {
        const int ch = chgrp * 3 + cc;
        // swizzled LDS read: linear byte = ch*8192 + (i0+col)*128 + g*16
        const int lin = ch * 8192 + (i0 + col) * 128 + g * 16;
        const int sw  = (col & 7) << 4;              // ((i0+col)&7)<<4, i0%16==0
        const bf16x8 a0 = *(const bf16x8*)(lds + (lin ^ sw));
        const bf16x8 a1 = *(const bf16x8*)(lds + ((lin + 64) ^ sw));
#pragma unroll
        for (int q = 0; q < 2; ++q) {
            f32x4 gre = {0.f, 0.f, 0.f, 0.f}, gim = {0.f, 0.f, 0.f, 0.f};
            gre = __builtin_amdgcn_mfma_f32_16x16x32_bf16(a0, bre[q][0], gre, 0, 0, 0);
            gre = __builtin_amdgcn_mfma_f32_16x16x32_bf16(a1, bre[q][1], gre, 0, 0, 0);
            gim = __builtin_amdgcn_mfma_f32_16x16x32_bf16(a0, bim[q][0], gim, 0, 0, 0);
            gim = __builtin_amdgcn_mfma_f32_16x16x32_bf16(a1, bim[q][1], gim, 0, 0, 0);
#pragma unroll
            for (int reg = 0; reg < 4; ++reg) {
                yre[q][cc] = fmaf(eyR[q][reg], gre[reg],
                              fmaf(-eyI[q][reg], gim[reg], yre[q][cc]));
                yim[q][cc] = fmaf(eyR[q][reg], gim[reg],
                              fmaf( eyI[q][reg], gre[reg], yim[q][cc]));
            }
        }
    }

    // reduce over g (lane bits 4,5), park partials in LDS
#pragma unroll
    for (int q = 0; q < 2; ++q) {
#pragma unroll
        for (int cc = 0; cc < 3; ++cc) {
            float vr = yre[q][cc], vi = yim[q][cc];
            vr += __shfl_xor(vr, 16); vi += __shfl_xor(vi, 16);
            vr += __shfl_xor(vr, 32); vi += __shfl_xor(vi, 32);
            if (g == 0)
                ylds[iq][chgrp * 3 + cc][q * 16 + col] = make_float2(vr, vi);
        }
    }
    __syncthreads();

    // ---- phase 3: fused combine epilogue (planar f32 out, proven) ----
    bool is64 = true;
#pragma unroll
    for (int i = 1; i < 32; i += 2) is64 = is64 && (sidx[i] == 0);
#pragma unroll
    for (int q = 0; q < 4; ++q) {
        const int item = tid + q * 1024;         // 32t x 4c x 32k = 4096
        const int kl = item & 31;
        const int c  = (item >> 5) & 3;
        const int t  = item >> 7;
        const int rt = is64 ? sidx[2 * t] : sidx[t];
        if (rt == r) {
            const float d = dcf[r * NK + k0 + kl];
            float ore = 0.f, oim = 0.f;
#pragma unroll
            for (int a = 0; a < NA; ++a) {
                const float p = phi[a * NT + t];
                const float2 v0 = ylds[0][a * 4 + c][kl];
                const float2 v1 = ylds[1][a * 4 + c][kl];
                const float2 v2 = ylds[2][a * 4 + c][kl];
                const float2 v3 = ylds[3][a * 4 + c][kl];
                ore = fmaf(p, (v0.x + v1.x) + (v2.x + v3.x), ore);
                oim = fmaf(p, (v0.y + v1.y) + (v2.y + v3.y), oim);
            }
            const int gid = t * 4096 + c * 1024 + k0 + kl;
            out[gid]        = ore * d;
            out[NOUT + gid] = oim * d;
        }
    }
}

// ---------------------------------------------------------------------------
extern "C" void kernel_launch(void* const* d_in, const int* in_sizes, int n_in,
                              void* d_out, int out_size, void* d_ws, size_t ws_size,
                              hipStream_t stream) {
    // size-signature input resolution (robust to permutation; doc order default)
    int ix = 0, i16a = 1, iphi = 2, i16b = 3, idcf = 4, isidx = 5;
    int f16[2]; int n16 = 0, fx = -1, fphi = -1, fdcf = -1, fsidx = -1;
    for (int i = 0; i < n_in; ++i) {
        const int s = in_sizes[i];
        if (s == 12288) fx = i;
        else if (s == 96) fphi = i;
        else if (s == 8192) fdcf = i;
        else if (s == 16384) { if (n16 < 2) f16[n16] = i; ++n16; }
        else if (s == 32 || s == 64) fsidx = i;
    }
    if (fx >= 0 && fphi >= 0 && fdcf >= 0 && fsidx >= 0 && n16 == 2) {
        ix = fx; iphi = fphi; idcf = fdcf; isidx = fsidx;
        i16a = f16[0]; i16b = f16[1];
    }

    static bool attr_set = false;
    if (!attr_set) {
        hipFuncSetAttribute((const void*)nudft_mono16,
                            hipFuncAttributeMaxDynamicSharedMemorySize,
                            SP_LDS_BYTES);
        attr_set = true;
    }

    nudft_mono16<<<NRK / 32, 1024, SP_LDS_BYTES, stream>>>(
        (const float*)d_in[ix], (const float*)d_in[i16a], (const float*)d_in[i16b],
        (const float*)d_in[iphi], (const float*)d_in[idcf], (const int*)d_in[isidx],
        (float*)d_out);
}